// Round 6
// baseline (104.189 us; speedup 1.0000x reference)
//
#include <hip/hip_runtime.h>
#include <hip/hip_bf16.h>

#define BB 4
#define LL 1024
#define DIMD 512
#define HH 8
#define EHD 64
#define NBUCK 1023

using f32x4 = __attribute__((ext_vector_type(4))) float;
using s16x8 = __attribute__((ext_vector_type(8))) short;

__device__ __forceinline__ ushort to_bf16(float x) {
    union { float f; unsigned u; } v; v.f = x;
    unsigned r = (v.u + 0x7FFFu + ((v.u >> 16) & 1u)) >> 16;
    return (ushort)r;
}

__device__ __forceinline__ void gl_lds16(const ushort* g, ushort* l) {
    __builtin_amdgcn_global_load_lds(
        (const __attribute__((address_space(1))) unsigned int*)g,
        (__attribute__((address_space(3))) unsigned int*)l, 16, 0, 0);
}

// ---------------------------------------------------------------------------
// bf16 conversion of x, W_in, W_out
// ---------------------------------------------------------------------------
#define XN  2097152
#define WIN 786432
#define WON 262144
__global__ __launch_bounds__(256) void cvt_bf16(const float* __restrict__ x,
                                                const float* __restrict__ wi,
                                                const float* __restrict__ wo,
                                                ushort* __restrict__ xb,
                                                ushort* __restrict__ wib,
                                                ushort* __restrict__ wob)
{
    int idx = (blockIdx.x * 256 + threadIdx.x) * 4;
    const float* src; ushort* dst; int off;
    if (idx < XN)            { src = x;  dst = xb;  off = idx; }
    else if (idx < XN + WIN) { src = wi; dst = wib; off = idx - XN; }
    else                     { src = wo; dst = wob; off = idx - XN - WIN; }
    float4 v = *(const float4*)&src[off];
    ushort4 o;
    o.x = to_bf16(v.x); o.y = to_bf16(v.y);
    o.z = to_bf16(v.z); o.w = to_bf16(v.w);
    *(ushort4*)&dst[off] = o;
}

// ---------------------------------------------------------------------------
// MFMA GEMM (unchanged from round 3)
// ---------------------------------------------------------------------------
template<int BN, int WMODE>
__global__ __launch_bounds__(256) void mfma_gemm(const ushort* __restrict__ A,
                                                 const ushort* __restrict__ B,
                                                 const float* __restrict__ bias,
                                                 float* __restrict__ outf,
                                                 ushort* __restrict__ outq,
                                                 ushort* __restrict__ outk,
                                                 ushort* __restrict__ outv,
                                                 const int* __restrict__ time_ids,
                                                 int M, int N, int K)
{
    constexpr int NREP = BN / 32;
    constexpr int SMEM_SZ = (WMODE == 1) ? 34816 : (16384 + BN * 128);
    __shared__ __align__(16) char smem[SMEM_SZ];
    ushort* Abuf = (ushort*)smem;
    ushort* Bbuf = (ushort*)(smem + 16384);

    const int t = threadIdx.x;
    const int lane = t & 63;
    const int w = t >> 6;
    const int l15 = lane & 15, lg = lane >> 4;
    const int wr = w >> 1, wc = w & 1;
    const int m0 = blockIdx.x * 128;
    const int n0 = blockIdx.y * BN;

    const int asub = lane >> 3;
    const int kc8 = (lane & 7) * 8;
    const int arow_base = w * 32;
    const int brow_base = w * (BN / 4);

    f32x4 acc[4][NREP];
    #pragma unroll
    for (int mf = 0; mf < 4; ++mf)
        #pragma unroll
        for (int nf = 0; nf < NREP; ++nf)
            acc[mf][nf] = {0.f, 0.f, 0.f, 0.f};

    for (int k0 = 0; k0 < K; k0 += 64) {
        #pragma unroll
        for (int i = 0; i < 4; ++i) {
            int row = arow_base + i * 8;
            gl_lds16(&A[(size_t)(m0 + row + asub) * K + k0 + kc8], &Abuf[row * 64]);
        }
        #pragma unroll
        for (int i = 0; i < BN / 32; ++i) {
            int row = brow_base + i * 8;
            gl_lds16(&B[(size_t)(n0 + row + asub) * K + k0 + kc8], &Bbuf[row * 64]);
        }
        __syncthreads();
        #pragma unroll
        for (int kk = 0; kk < 2; ++kk) {
            s16x8 af[4], bf[NREP];
            #pragma unroll
            for (int mf = 0; mf < 4; ++mf)
                af[mf] = *(const s16x8*)&Abuf[(wr * 64 + mf * 16 + l15) * 64 + kk * 32 + lg * 8];
            #pragma unroll
            for (int nf = 0; nf < NREP; ++nf)
                bf[nf] = *(const s16x8*)&Bbuf[(wc * (BN / 2) + nf * 16 + l15) * 64 + kk * 32 + lg * 8];
            #pragma unroll
            for (int mf = 0; mf < 4; ++mf)
                #pragma unroll
                for (int nf = 0; nf < NREP; ++nf)
                    acc[mf][nf] = __builtin_amdgcn_mfma_f32_16x16x32_bf16(af[mf], bf[nf], acc[mf][nf], 0, 0, 0);
        }
        __syncthreads();
    }

    if (WMODE == 0) {
        float bv[NREP];
        #pragma unroll
        for (int nf = 0; nf < NREP; ++nf) bv[nf] = bias[n0 + wc * (BN / 2) + nf * 16 + l15];
        #pragma unroll
        for (int mf = 0; mf < 4; ++mf)
            #pragma unroll
            for (int r = 0; r < 4; ++r) {
                int m = m0 + wr * 64 + mf * 16 + lg * 4 + r;
                #pragma unroll
                for (int nf = 0; nf < NREP; ++nf)
                    outf[(size_t)m * N + n0 + wc * (BN / 2) + nf * 16 + l15] = acc[mf][nf][r] + bv[nf];
            }
    } else {
        const int which = n0 >> 9;
        if (which < 2) {
            const int h = ((n0 & 511) + wc * 64) >> 6;
            ushort* dst = (which == 0) ? outq : outk;
            float bv[4];
            #pragma unroll
            for (int nf = 0; nf < 4; ++nf) bv[nf] = bias[n0 + wc * 64 + nf * 16 + l15];
            const float L2T = 13.287712379549449f;  // log2(10000)
            float inv0 = exp2f(-(float)(l15)      * (L2T / 32.f));
            float inv1 = exp2f(-(float)(16 + l15) * (L2T / 32.f));
            #pragma unroll
            for (int mf = 0; mf < 4; ++mf)
                #pragma unroll
                for (int r = 0; r < 4; ++r) {
                    int m = m0 + wr * 64 + mf * 16 + lg * 4 + r;
                    int b = m >> 10, li = m & (LL - 1);
                    int tt = time_ids[b * LL + li];
                    size_t rowbase = (((size_t)(b * HH + h)) * LL + li) * EHD;
                    #pragma unroll
                    for (int nf = 0; nf < 2; ++nf) {
                        float ang = (float)tt * (nf ? inv1 : inv0);
                        float c, s;
                        sincosf(ang, &s, &c);
                        float v1 = acc[mf][nf][r] + bv[nf];
                        float v2 = acc[mf][nf + 2][r] + bv[nf + 2];
                        dst[rowbase + nf * 16 + l15]      = to_bf16(v1 * c - v2 * s);
                        dst[rowbase + 32 + nf * 16 + l15] = to_bf16(v2 * c + v1 * s);
                    }
                }
        } else {
            ushort* T = (ushort*)smem;   // [128][136]
            float bv[4];
            #pragma unroll
            for (int nf = 0; nf < 4; ++nf) bv[nf] = bias[n0 + wc * 64 + nf * 16 + l15];
            #pragma unroll
            for (int mf = 0; mf < 4; ++mf)
                #pragma unroll
                for (int nf = 0; nf < 4; ++nf) {
                    int n = wc * 64 + nf * 16 + l15;
                    int mb = wr * 64 + mf * 16 + lg * 4;
                    ushort4 pk;
                    pk.x = to_bf16(acc[mf][nf][0] + bv[nf]);
                    pk.y = to_bf16(acc[mf][nf][1] + bv[nf]);
                    pk.z = to_bf16(acc[mf][nf][2] + bv[nf]);
                    pk.w = to_bf16(acc[mf][nf][3] + bv[nf]);
                    *(ushort4*)&T[n * 136 + mb] = pk;
                }
            __syncthreads();
            const int b = m0 >> 10, li0 = m0 & (LL - 1);
            const int hbase = (n0 & 511) >> 6;
            #pragma unroll
            for (int it = 0; it < 8; ++it) {
                int n = it * 16 + (t >> 4);
                int mc = (t & 15) * 8;
                uint4 val = *(const uint4*)&T[n * 136 + mc];
                int h = hbase + (n >> 6);
                int e = n & 63;
                *(uint4*)&outv[(((size_t)(b * HH + h)) * EHD + e) * LL + li0 + mc] = val;
            }
        }
    }
}

// ---------------------------------------------------------------------------
// Histogram of V rows by time value: W[bh][e][tau] = sum_{l: t[l]=tau} V[l][e]
// One block per (bh, group of 8 e-rows). LDS f32 atomics, then bf16 store.
// ---------------------------------------------------------------------------
__global__ __launch_bounds__(256) void hist_v(const ushort* __restrict__ vt,
                                              const int* __restrict__ time_ids,
                                              ushort* __restrict__ Wt)
{
    __shared__ float Wl[512 * 8];     // [tau][e8] 16 KB
    __shared__ int tl[1024];
    const int t = threadIdx.x;
    const int bh = blockIdx.x, b = bh >> 3;
    const int eg = blockIdx.y;        // 0..7
    for (int i = t; i < 4096; i += 256) Wl[i] = 0.f;
    for (int i = t; i < 1024; i += 256) tl[i] = time_ids[b * LL + i];
    __syncthreads();
    const int e = t & 7, chunk = t >> 3;
    const ushort* vrow = vt + ((size_t)bh * EHD + eg * 8 + e) * LL;
    #pragma unroll 4
    for (int l = chunk * 32; l < chunk * 32 + 32; ++l) {
        float v = __uint_as_float((unsigned)vrow[l] << 16);
        atomicAdd(&Wl[tl[l] * 8 + e], v);
    }
    __syncthreads();
    for (int i = t; i < 4096; i += 256) {
        int ee = i >> 9, tau = i & 511;
        Wt[((size_t)bh * EHD + eg * 8 + ee) * 512 + tau] = to_bf16(Wl[tau * 8 + ee]);
    }
}

// ---------------------------------------------------------------------------
// Toeplitz GEMM: O2[bh][tq][e] = sum_tau pt[tq - tau + 511] * W[bh][e][tau].
// Reversed table makes A-fragments contiguous loads (no gathers).
// ---------------------------------------------------------------------------
__global__ __launch_bounds__(256) void o2_gemm(const ushort* __restrict__ Wt,
                                               const float* __restrict__ post_table,
                                               float* __restrict__ O2)
{
    __shared__ __align__(16) float rv[1024];   // reversed pt for this head
    const int t = threadIdx.x;
    const int bh = blockIdx.x, h = bh & 7;
    const int tq0 = blockIdx.y * 64;
    for (int i = t; i < NBUCK; i += 256) rv[i] = post_table[h * NBUCK + 1022 - i];
    __syncthreads();
    const int lane = t & 63, w = t >> 6;
    const int l15 = lane & 15, lg = lane >> 4;
    const int myrow = tq0 + w * 16 + l15;
    const ushort* wpan = Wt + (size_t)bh * EHD * 512;

    f32x4 acc[4];
    #pragma unroll
    for (int ei = 0; ei < 4; ++ei) acc[ei] = {0.f, 0.f, 0.f, 0.f};

    for (int ts = 0; ts < 512; ts += 32) {
        int base = 511 - myrow + ts + lg * 8;   // in [0, 1015]
        s16x8 af;
        #pragma unroll
        for (int j = 0; j < 8; ++j) af[j] = (short)to_bf16(rv[base + j]);
        #pragma unroll
        for (int ei = 0; ei < 4; ++ei) {
            s16x8 bf = *(const s16x8*)&wpan[(size_t)(ei * 16 + l15) * 512 + ts + lg * 8];
            acc[ei] = __builtin_amdgcn_mfma_f32_16x16x32_bf16(af, bf, acc[ei], 0, 0, 0);
        }
    }
    #pragma unroll
    for (int ei = 0; ei < 4; ++ei)
        #pragma unroll
        for (int r = 0; r < 4; ++r) {
            int row = tq0 + w * 16 + lg * 4 + r;
            O2[((size_t)bh * 512 + row) * 64 + ei * 16 + l15] = acc[ei][r];
        }
}

// ---------------------------------------------------------------------------
// MFMA attention (softmax path only; post-bias path moved to hist_v/o2_gemm).
// 2-phase double-buffered staging, 1 barrier/tile, defer-max (THR=8).
// ---------------------------------------------------------------------------
__global__ __launch_bounds__(256, 3) void attn_mfma(const ushort* __restrict__ qb,
                                                    const ushort* __restrict__ kb,
                                                    const ushort* __restrict__ vt,
                                                    const int* __restrict__ time_ids,
                                                    const float* __restrict__ rel_table,
                                                    const float* __restrict__ O2g,
                                                    ushort* __restrict__ ao)
{
    __shared__ __align__(16) float rt_s[1024];        // pre-scaled by log2(e)
    __shared__ __align__(16) int   tid4_s[1024];      // time value * 4 (byte off)
    __shared__ __align__(16) ushort Kbuf[2][4096];
    __shared__ __align__(16) ushort Vbuf[2][4096];
    __shared__ __align__(16) ushort Ps[4][1024];

    const int t = threadIdx.x;
    const int lane = t & 63;
    const int w = t >> 6;
    const int l15 = lane & 15, lg = lane >> 4;
    const int bh = blockIdx.x, b = bh >> 3, h = bh & 7;
    const int wq0 = blockIdx.y * 64 + w * 16;

    const float L2E = 1.4426950408889634f;
    for (int i = t; i < NBUCK; i += 256) rt_s[i] = rel_table[h * NBUCK + i] * L2E;
    const int* tid_b = time_ids + b * LL;
    #pragma unroll
    for (int i = 0; i < 4; ++i) tid4_s[i * 256 + t] = tid_b[i * 256 + t] * 4;

    const ushort* qpan = qb + (size_t)bh * LL * EHD;
    const ushort* kpan = kb + (size_t)bh * LL * EHD;
    const ushort* vpan = vt + (size_t)bh * EHD * LL;

    s16x8 qf[2];
    #pragma unroll
    for (int ec = 0; ec < 2; ++ec)
        qf[ec] = *(const s16x8*)&qpan[(size_t)(wq0 + l15) * EHD + ec * 32 + lg * 8];

    int4 tq4 = *(const int4*)&tid_b[wq0 + lg * 4];
    const int tqraw[4] = {tq4.x, tq4.y, tq4.z, tq4.w};
    const int tqB[4] = {(tq4.x + 511) * 4, (tq4.y + 511) * 4,
                        (tq4.z + 511) * 4, (tq4.w + 511) * 4};

    const int srow = lane >> 3;
    const int sswz = (lane & 7) ^ srow;

    #define STAGE(BUF, K0)                                                        \
        do {                                                                      \
            int r0 = w * 8 + srow;                                                \
            gl_lds16(&kpan[(size_t)((K0) + r0) * EHD + sswz * 8], &Kbuf[BUF][w * 8 * 64]);       \
            gl_lds16(&vpan[(size_t)r0 * LL + (K0) + sswz * 8],    &Vbuf[BUF][w * 8 * 64]);       \
            gl_lds16(&kpan[(size_t)((K0) + r0 + 32) * EHD + sswz * 8], &Kbuf[BUF][(32 + w * 8) * 64]); \
            gl_lds16(&vpan[(size_t)(r0 + 32) * LL + (K0) + sswz * 8],  &Vbuf[BUF][(32 + w * 8) * 64]); \
        } while (0)

    float mrow[4], drow[4];
    f32x4 acc1[4];
    #pragma unroll
    for (int r = 0; r < 4; ++r) { mrow[r] = -1e30f; drow[r] = 0.f; }
    #pragma unroll
    for (int ei = 0; ei < 4; ++ei) acc1[ei] = {0.f, 0.f, 0.f, 0.f};

    ushort* ps = Ps[w];

    STAGE(0, 0);
    __syncthreads();

    for (int kt = 0; kt < 16; ++kt) {
        const int cur = kt & 1;
        const int k0 = kt * 64;
        if (kt < 15) STAGE(cur ^ 1, k0 + 64);

        const char* Kc = (const char*)Kbuf[cur];
        const char* Vc = (const char*)Vbuf[cur];

        // ---- QK^T ----
        f32x4 sc[4];
        #pragma unroll
        for (int ci = 0; ci < 4; ++ci) sc[ci] = {0.f, 0.f, 0.f, 0.f};
        __builtin_amdgcn_s_setprio(1);
        #pragma unroll
        for (int ec = 0; ec < 2; ++ec)
            #pragma unroll
            for (int ci = 0; ci < 4; ++ci) {
                int row = ci * 16 + l15;
                s16x8 kf = *(const s16x8*)(Kc + row * 128 +
                                           ((ec * 64 + lg * 16) ^ ((row & 7) << 4)));
                sc[ci] = __builtin_amdgcn_mfma_f32_16x16x32_bf16(qf[ec], kf, sc[ci], 0, 0, 0);
            }
        __builtin_amdgcn_s_setprio(0);

        // ---- V fragments ----
        s16x8 vf[4][2];
        #pragma unroll
        for (int ei = 0; ei < 4; ++ei)
            #pragma unroll
            for (int kk = 0; kk < 2; ++kk) {
                int row = ei * 16 + l15;
                vf[ei][kk] = *(const s16x8*)(Vc + row * 128 +
                                             ((kk * 64 + lg * 16) ^ ((row & 7) << 4)));
            }

        // ---- rel bias (log2 domain, byte-offset gather) ----
        int tkB[4];
        #pragma unroll
        for (int ci = 0; ci < 4; ++ci) tkB[ci] = tid4_s[k0 + ci * 16 + l15];
        #pragma unroll
        for (int ci = 0; ci < 4; ++ci)
            #pragma unroll
            for (int r = 0; r < 4; ++r)
                sc[ci][r] = sc[ci][r] * 0.18033688011111793f +
                            *(const float*)((const char*)rt_s + (tqB[r] - tkB[ci]));

        // ---- online softmax (base 2) with defer-max ----
        float mn[4];
        bool grew = false;
        #pragma unroll
        for (int r = 0; r < 4; ++r) {
            float mx = fmaxf(fmaxf(sc[0][r], sc[1][r]), fmaxf(sc[2][r], sc[3][r]));
            #pragma unroll
            for (int d = 1; d < 16; d <<= 1) mx = fmaxf(mx, __shfl_xor(mx, d));
            mn[r] = fmaxf(mrow[r], mx);
            grew = grew || (mn[r] > mrow[r] + 8.f);
        }
        if (__any(grew)) {
            #pragma unroll
            for (int r = 0; r < 4; ++r) {
                float fs = exp2f(mrow[r] - mn[r]);
                mrow[r] = mn[r];
                drow[r] *= fs;
                #pragma unroll
                for (int ei = 0; ei < 4; ++ei) acc1[ei][r] *= fs;
            }
        }
        #pragma unroll
        for (int r = 0; r < 4; ++r) {
            float rsum = 0.f;
            #pragma unroll
            for (int ci = 0; ci < 4; ++ci) {
                float p = exp2f(sc[ci][r] - mrow[r]);
                sc[ci][r] = p;
                rsum += p;
            }
            #pragma unroll
            for (int d = 1; d < 16; d <<= 1) rsum += __shfl_xor(rsum, d);
            drow[r] += rsum;
            int row = lg * 4 + r;
            #pragma unroll
            for (int ci = 0; ci < 4; ++ci)
                *(ushort*)((char*)ps + row * 128 + ((ci * 32 + l15 * 2) ^ ((row & 7) << 4)))
                    = to_bf16(sc[ci][r]);
        }
        asm volatile("s_waitcnt lgkmcnt(0)" ::: "memory");

        // ---- P @ V ----
        #pragma unroll
        for (int kk = 0; kk < 2; ++kk) {
            s16x8 af = *(const s16x8*)((const char*)ps + l15 * 128 +
                                       ((kk * 64 + lg * 16) ^ ((l15 & 7) << 4)));
            __builtin_amdgcn_s_setprio(1);
            #pragma unroll
            for (int ei = 0; ei < 4; ++ei)
                acc1[ei] = __builtin_amdgcn_mfma_f32_16x16x32_bf16(af, vf[ei][kk], acc1[ei], 0, 0, 0);
            __builtin_amdgcn_s_setprio(0);
        }

        __syncthreads();
    }

    float inv[4];
    #pragma unroll
    for (int r = 0; r < 4; ++r) inv[r] = 1.f / drow[r];
    #pragma unroll
    for (int ei = 0; ei < 4; ++ei) {
        #pragma unroll
        for (int r = 0; r < 4; ++r) {
            int row = wq0 + lg * 4 + r;
            int col = h * EHD + ei * 16 + l15;
            float o2v = O2g[((size_t)bh * 512 + tqraw[r]) * 64 + ei * 16 + l15];
            ao[(size_t)(b * LL + row) * DIMD + col] = to_bf16(acc1[ei][r] * inv[r] + o2v);
        }
    }
}

extern "C" void kernel_launch(void* const* d_in, const int* in_sizes, int n_in,
                              void* d_out, int out_size, void* d_ws, size_t ws_size,
                              hipStream_t stream)
{
    const float* x        = (const float*)d_in[0];
    const int*   time_ids = (const int*)d_in[2];
    const float* W_in     = (const float*)d_in[3];
    const float* b_in     = (const float*)d_in[4];
    const float* W_out    = (const float*)d_in[5];
    const float* b_out    = (const float*)d_in[6];
    const float* rel_t    = (const float*)d_in[7];
    const float* post_t   = (const float*)d_in[8];
    float* out = (float*)d_out;

    ushort* wsu = (ushort*)d_ws;
    ushort* xb  = wsu;
    ushort* wib = xb + XN;
    ushort* wob = wib + WIN;
    ushort* qbf = wob + WON;
    ushort* kbf = qbf + XN;
    ushort* vtb = kbf + XN;
    ushort* aob = vtb + XN;
    ushort* Wt  = aob + XN;                       // 1,048,576 bf16
    float*  O2  = (float*)(Wt + 1048576);         // 1,048,576 f32

    cvt_bf16<<<3072, 256, 0, stream>>>(x, W_in, W_out, xb, wib, wob);
    mfma_gemm<128, 1><<<dim3(32, 12), 256, 0, stream>>>(xb, wib, b_in,
                                                        nullptr, qbf, kbf, vtb,
                                                        time_ids,
                                                        BB * LL, 3 * DIMD, DIMD);
    hist_v<<<dim3(32, 8), 256, 0, stream>>>(vtb, time_ids, Wt);
    o2_gemm<<<dim3(32, 8), 256, 0, stream>>>(Wt, post_t, O2);
    attn_mfma<<<dim3(32, 16), 256, 0, stream>>>(qbf, kbf, vtb, time_ids,
                                                rel_t, O2, aob);
    mfma_gemm<64, 0><<<dim3(32, 8), 256, 0, stream>>>(aob, wob, b_out,
                                                      out, nullptr, nullptr, nullptr,
                                                      nullptr,
                                                      BB * LL, DIMD, DIMD);
}